// Round 10
// baseline (46087.564 us; speedup 1.0000x reference)
//
#include <hip/hip_runtime.h>
#include <hip/hip_bf16.h>
#include <math.h>

#define NB 64
#define NT 512
#define NDIN 256
#define NH 1024
#define NG 4096
#define NDOUT 256

#define GRID 512
#define SKS 4          // splitK slices
#define KUP 10         // ku units per slice (40 total, 3-term merged per ku)

typedef __attribute__((ext_vector_type(8))) short short8;
typedef __attribute__((ext_vector_type(4))) float float4v;

__device__ __forceinline__ float sigf(float v) { return 1.0f / (1.0f + expf(-v)); }

__device__ __forceinline__ unsigned short bf_hi(float v, float* back) {
    __hip_bfloat16 b = __float2bfloat16(v);
    *back = __bfloat162float(b);
    union { __hip_bfloat16 b; unsigned short u; } cv; cv.b = b;
    return cv.u;
}

__global__ void zero_kernel(float* __restrict__ p, int n) {
    int i = blockIdx.x * 256 + threadIdx.x;
    if (i < n) p[i] = 0.0f;
}

// W (= [Wx;Wh], 1280 x 4096) -> B-frag order [nb(256)][ku(40)][lane(64)][j(8)], hi/lo
__global__ void packW_kernel(const float* __restrict__ Wx, const float* __restrict__ Wh,
                             unsigned short* __restrict__ W0f, unsigned short* __restrict__ W1f) {
    int e = blockIdx.x * 256 + threadIdx.x;
    if (e >= 1280 * 4096) return;
    int k = e >> 12, n = e & 4095;
    float w = (k < NDIN) ? Wx[(size_t)k * NG + n] : Wh[(size_t)(k - NDIN) * NG + n];
    float back;
    unsigned short w0 = bf_hi(w, &back);
    unsigned short w1 = bf_hi(w - back, &back);
    int nb = n >> 4, nl = n & 15, ku = k >> 5, kr = k & 31;
    int lane = (kr >> 3) * 16 + nl, j = kr & 7;
    size_t off = (((size_t)nb * 40 + ku) * 64 + lane) * 8 + j;
    W0f[off] = w0; W1f[off] = w1;
}

// x ([64][512][256]) -> A-frag order [t][ku(8)][mb(4)][lane(64)][j(8)], hi/lo
__global__ void packX_kernel(const float* __restrict__ x,
                             unsigned short* __restrict__ xf0, unsigned short* __restrict__ xf1) {
    int e = blockIdx.x * 256 + threadIdx.x;
    if (e >= NB * NT * NDIN) return;
    int k = e & 255, t = (e >> 8) & 511, m = e >> 17;
    float v = x[e];
    float back;
    unsigned short a0 = bf_hi(v, &back);
    unsigned short a1 = bf_hi(v - back, &back);
    int ku = k >> 5, kr = k & 31, mb = m >> 4;
    int lane = (kr >> 3) * 16 + (m & 15), j = kr & 7;
    size_t off = ((((size_t)t * 8 + ku) * 4 + mb) * 64 + lane) * 8 + j;
    xf0[off] = a0; xf1[off] = a1;
}

// Wo (1024 x 256) -> B-frag order [nb(16)][ku(32)][lane(64)][j(8)], hi/lo
__global__ void packWo_kernel(const float* __restrict__ Wo,
                              unsigned short* __restrict__ Wo0f, unsigned short* __restrict__ Wo1f) {
    int e = blockIdx.x * 256 + threadIdx.x;
    if (e >= NH * NDOUT) return;
    int k = e >> 8, n = e & 255;
    float w = Wo[e];
    float back;
    unsigned short w0 = bf_hi(w, &back);
    unsigned short w1 = bf_hi(w - back, &back);
    int nb = n >> 4, nl = n & 15, ku = k >> 5, kr = k & 31;
    int lane = (kr >> 3) * 16 + nl, j = kr & 7;
    size_t off = (((size_t)nb * 32 + ku) * 64 + lane) * 8 + j;
    Wo0f[off] = w0; Wo1f[off] = w1;
}

// Round-5 PROVEN grid barrier (passed correctness): threadfence + acq-rel tree.
__device__ __forceinline__ void gridbar(unsigned* bar, unsigned k) {
    __syncthreads();
    if (threadIdx.x == 0) {
        __threadfence();   // release
        const int grp = blockIdx.x >> 5;   // 16 groups of 32
        unsigned* gcnt = bar + 64 + grp * 32;
        unsigned* grel = bar + 64 + 512 + grp * 32;
        unsigned a = __hip_atomic_fetch_add(gcnt, 1u, __ATOMIC_ACQ_REL, __HIP_MEMORY_SCOPE_AGENT) + 1;
        if (a == k * 32u) {
            unsigned r = __hip_atomic_fetch_add(bar, 1u, __ATOMIC_ACQ_REL, __HIP_MEMORY_SCOPE_AGENT) + 1;
            if (r == k * 16u) {
                __hip_atomic_store(bar + 8, k, __ATOMIC_RELEASE, __HIP_MEMORY_SCOPE_AGENT);
            } else {
                while (__hip_atomic_load(bar + 8, __ATOMIC_RELAXED, __HIP_MEMORY_SCOPE_AGENT) < k)
                    __builtin_amdgcn_s_sleep(1);
            }
            __hip_atomic_store(grel, k, __ATOMIC_RELEASE, __HIP_MEMORY_SCOPE_AGENT);
        } else {
            while (__hip_atomic_load(grel, __ATOMIC_RELAXED, __HIP_MEMORY_SCOPE_AGENT) < k)
                __builtin_amdgcn_s_sleep(1);
        }
        __threadfence();   // acquire
    }
    __syncthreads();
}

__device__ __forceinline__ const unsigned short* abase(
    const unsigned short* xf0, const unsigned short* xf1,
    const unsigned short* hf, int t, int buf, int ku, int v) {
    if (ku < 8) return (v ? xf1 : xf0) + ((size_t)t * 8 + ku) * 2048;
    return hf + ((size_t)(v * 2 + buf) * 32 + (ku - 8)) * 2048;
}

__global__ __launch_bounds__(256, 2) void persist(
    const unsigned short* __restrict__ W0f, const unsigned short* __restrict__ W1f,
    const unsigned short* __restrict__ xf0, const unsigned short* __restrict__ xf1,
    const unsigned short* __restrict__ Wo0f, const unsigned short* __restrict__ Wo1f,
    unsigned short* __restrict__ hf, float* __restrict__ cst,
    float* __restrict__ zpart, float* __restrict__ opart, unsigned* __restrict__ bar,
    const float* __restrict__ bias, const float* __restrict__ bo,
    float* __restrict__ out)
{
    __shared__ unsigned short W0l[2 * KUP * 512];   // 20 KB: block's W0 slice
    __shared__ unsigned short W1l[2 * KUP * 512];   // 20 KB: block's W1 slice
    __shared__ unsigned short As[2 * 4 * 512];      // 8 KB: A hi/lo for one ku
    __shared__ const unsigned short* tA[48];
    __shared__ const unsigned short* tW[48];
    __shared__ float zs[4 * 260];

    const int bid = blockIdx.x, tid = threadIdx.x;
    const int lane = tid & 63, w = tid >> 6;
    const int ct = bid >> 2, s = bid & 3;           // z role: 128 ct x 4 K-slices
    const int cm = bid >> 2, cjc = (bid & 3) << 8;  // combine role (bid<256)

    // ---- one-time: preload this block's W slice into LDS (fences can't evict LDS)
    #pragma unroll
    for (int i = 0; i < 10; ++i) {
        int c = i * 256 + tid;                      // [0,2560)
        int half = c / 1280, rem = c % 1280;
        int nl = rem / 640, kuL = (rem % 640) >> 6, e16 = rem & 63;
        const unsigned short* src = (half ? W1f : W0f)
            + (((size_t)(ct * 2 + nl) * 40 + (s * KUP + kuL)) * 64) * 8 + e16 * 8;
        unsigned short* dst = (half ? W1l : W0l) + ((nl * KUP + kuL) * 512 + e16 * 8);
        *(short8*)dst = *(const short8*)src;
    }
    __syncthreads();

    const int c0 = tid * 2, c1 = tid * 2 + 1;
    const int v0 = c0 >> 8, mb0 = (c0 >> 6) & 3, rem0 = c0 & 63;
    const int v1 = c1 >> 8, mb1 = (c1 >> 6) & 3, rem1 = c1 & 63;

    for (int t = 0; t <= NT; ++t) {
        const int buf = t & 1;

        // ================= PHASE A =================
        if (t < NT) {
            float4v acc[2];
            acc[0] = (float4v){0.f, 0.f, 0.f, 0.f};
            acc[1] = (float4v){0.f, 0.f, 0.f, 0.f};

            short8 pr0, pr1;
            {   // prologue: load ku 0
                int ku = s * KUP;
                pr0 = *(const short8*)(abase(xf0, xf1, hf, t, buf, ku, v0) + mb0 * 512 + rem0 * 8);
                pr1 = *(const short8*)(abase(xf0, xf1, hf, t, buf, ku, v1) + mb1 * 512 + rem1 * 8);
            }
            for (int i2 = 0; i2 < KUP; ++i2) {
                *(short8*)&As[(v0 * 4 + mb0) * 512 + rem0 * 8] = pr0;
                *(short8*)&As[(v1 * 4 + mb1) * 512 + rem1 * 8] = pr1;
                __syncthreads();
                if (i2 < KUP - 1) {
                    int ku = s * KUP + i2 + 1;
                    pr0 = *(const short8*)(abase(xf0, xf1, hf, t, buf, ku, v0) + mb0 * 512 + rem0 * 8);
                    pr1 = *(const short8*)(abase(xf0, xf1, hf, t, buf, ku, v1) + mb1 * 512 + rem1 * 8);
                }
                short8 A0 = *(const short8*)&As[(0 * 4 + w) * 512 + lane * 8];
                short8 A1 = *(const short8*)&As[(1 * 4 + w) * 512 + lane * 8];
                #pragma unroll
                for (int nl = 0; nl < 2; ++nl) {
                    short8 Wh0 = *(const short8*)&W0l[(nl * KUP + i2) * 512 + lane * 8];
                    short8 Wl1 = *(const short8*)&W1l[(nl * KUP + i2) * 512 + lane * 8];
                    acc[nl] = __builtin_amdgcn_mfma_f32_16x16x32_bf16(A0, Wh0, acc[nl], 0, 0, 0);
                    acc[nl] = __builtin_amdgcn_mfma_f32_16x16x32_bf16(A0, Wl1, acc[nl], 0, 0, 0);
                    acc[nl] = __builtin_amdgcn_mfma_f32_16x16x32_bf16(A1, Wh0, acc[nl], 0, 0, 0);
                }
                __syncthreads();
            }
            // epilogue: zpart[(s*64 + m)*NG + n], m = w*16+q4*4+r (round-5 layout)
            const int q4 = lane >> 4, nl16 = lane & 15;
            #pragma unroll
            for (int nl = 0; nl < 2; ++nl)
                #pragma unroll
                for (int r = 0; r < 4; ++r)
                    zpart[((size_t)(s * 64 + w * 16 + q4 * 4 + r)) * NG
                          + (ct * 2 + nl) * 16 + nl16] = acc[nl][r];
        }
        // proj blocks [256,288): project hf[buf] (= h_t) -> opart (round-5 verbatim)
        if (bid >= 256 && bid < 288) {
            const int pb = bid - 256;
            const int pnb = pb >> 1, pksl = pb & 1;
            for (int i = tid; i < 48; i += 256) {
                int u = pksl * 48 + i, q = u / 32, ku = u % 32;
                int v = (q == 2);
                tA[i] = hf + (((size_t)(v * 2 + buf) * 32 + ku) * 4) * 512;
                tW[i] = ((q == 1) ? Wo1f : Wo0f) + (size_t)pnb * 32 * 512 + (size_t)ku * 512;
            }
            __syncthreads();
            float4v pacc = (float4v){0.f, 0.f, 0.f, 0.f};
            #pragma unroll 6
            for (int i = 0; i < 48; ++i) {
                short8 A = *(const short8*)(tA[i] + w * 512 + lane * 8);
                short8 Bv = *(const short8*)(tW[i] + lane * 8);
                pacc = __builtin_amdgcn_mfma_f32_16x16x32_bf16(A, Bv, pacc, 0, 0, 0);
            }
            const int q4 = lane >> 4, nl16 = lane & 15;
            #pragma unroll
            for (int r = 0; r < 4; ++r)
                opart[((size_t)(pksl * 64 + w * 16 + q4 * 4 + r)) * NDOUT
                      + pnb * 16 + nl16] = pacc[r];
        }

        gridbar(bar, 2 * (unsigned)t + 1);

        // ================= PHASE B =================
        if (t < NT && bid < 256) {                    // combine (round-5 verbatim, SK=4)
            const int m = cm, jc = cjc;
            for (int rep = 0; rep < 4; ++rep) {
                const int j = jc + rep * 64 + lane;
                float sum = 0.f;
                #pragma unroll
                for (int sI = 0; sI < SKS; ++sI)
                    sum += zpart[((size_t)(sI * 64 + m)) * NG + w * NH + j];
                zs[w * 260 + rep * 64 + lane] = sum;
            }
            __syncthreads();
            {
                const int jl = tid, j = jc + jl;
                float zi = zs[0 * 260 + jl] + bias[j];
                float zf = zs[1 * 260 + jl] + bias[NH + j];
                float zg = zs[2 * 260 + jl] + bias[2 * NH + j];
                float zo = zs[3 * 260 + jl] + bias[3 * NH + j];
                float iv = sigf(zi), fv = sigf(zf), gv = tanhf(zg), ov = sigf(zo);
                const size_t ci = (size_t)m * NH + j;
                float cv = fv * cst[ci] + iv * gv;
                cst[ci] = cv;
                float hv = ov * tanhf(cv);
                float back;
                unsigned short h0 = bf_hi(hv, &back);
                unsigned short h1 = bf_hi(hv - back, &back);
                const int nbuf = (t + 1) & 1;
                int ku = j >> 5, kr = j & 31, mb2 = m >> 4;
                int lane2 = (kr >> 3) * 16 + (m & 15), jj = kr & 7;
                size_t base = (((size_t)nbuf * 32 + ku) * 4 + mb2) * 512 + lane2 * 8 + jj;
                hf[base] = h0;
                hf[base + 131072] = h1;   // v=1 stride
            }
        }
        if (bid >= 288 && bid < 320 && t >= 1) {      // out-reduce row t-1 (round-5 verbatim)
            const int ob = bid - 288;
            const int b0 = ob * 512;
            #pragma unroll
            for (int rr = 0; rr < 2; ++rr) {
                const int e = b0 + rr * 256 + tid;
                const int m = e >> 8, oc = e & 255;
                float v = opart[(size_t)m * NDOUT + oc]
                        + opart[(size_t)(64 + m) * NDOUT + oc] + bo[oc];
                out[((size_t)m * NT + (t - 1)) * NDOUT + oc] = fmaxf(v, 0.f);
            }
        }

        gridbar(bar, 2 * (unsigned)t + 2);
    }
}

extern "C" void kernel_launch(void* const* d_in, const int* in_sizes, int n_in,
                              void* d_out, int out_size, void* d_ws, size_t ws_size,
                              hipStream_t stream) {
    const float* x  = (const float*)d_in[0];
    const float* Wx = (const float*)d_in[1];
    const float* Wh = (const float*)d_in[2];
    const float* b  = (const float*)d_in[3];
    const float* Wo = (const float*)d_in[4];
    const float* bo = (const float*)d_in[5];
    float* out = (float*)d_out;
    char* ws = (char*)d_ws;

    size_t off = 0;
    unsigned* bar = (unsigned*)(ws + off);            off += 8192;
    float* cst    = (float*)(ws + off);               off += (size_t)NB * NH * 4;               // 256 KB
    unsigned short* hf = (unsigned short*)(ws + off); off += (size_t)2 * 2 * 32 * 4 * 512 * 2;  // 512 KB
    size_t zero_floats = off / 4;                     // bar + cst + hf zeroed
    float* opart = (float*)(ws + off);                off += (size_t)2 * NB * NDOUT * 4;        // 128 KB
    float* zpart = (float*)(ws + off);                off += (size_t)SKS * NB * NG * 4;         // 4 MB
    unsigned short* W0f = (unsigned short*)(ws + off); off += (size_t)1280 * 4096 * 2;
    unsigned short* W1f = (unsigned short*)(ws + off); off += (size_t)1280 * 4096 * 2;
    unsigned short* Wo0f = (unsigned short*)(ws + off); off += (size_t)NH * NDOUT * 2;
    unsigned short* Wo1f = (unsigned short*)(ws + off); off += (size_t)NH * NDOUT * 2;
    unsigned short* xf0 = (unsigned short*)(ws + off); off += (size_t)NB * NT * NDIN * 2;
    unsigned short* xf1 = (unsigned short*)(ws + off); off += (size_t)NB * NT * NDIN * 2;

    zero_kernel<<<(int)((zero_floats + 255) / 256), 256, 0, stream>>>((float*)ws, (int)zero_floats);
    packW_kernel<<<(1280 * 4096 + 255) / 256, 256, 0, stream>>>(Wx, Wh, W0f, W1f);
    packX_kernel<<<(NB * NT * NDIN + 255) / 256, 256, 0, stream>>>(x, xf0, xf1);
    packWo_kernel<<<(NH * NDOUT + 255) / 256, 256, 0, stream>>>(Wo, Wo0f, Wo1f);

    persist<<<GRID, 256, 0, stream>>>(W0f, W1f, xf0, xf1, Wo0f, Wo1f, hf, cst,
                                      zpart, opart, bar, b, bo, out);
}

// Round 11
// 6327.771 us; speedup vs baseline: 7.2834x; 7.2834x over previous
//
#include <hip/hip_runtime.h>
#include <hip/hip_bf16.h>
#include <math.h>

#define NB 64
#define NT 512
#define NDIN 256
#define NH 1024
#define NG 4096
#define NDOUT 256

// grid roles: [0,64) z+combine, [64,80) proj, [80,88) out-reduce
#define GRIDN 88
#define LDSB 148992   // 128K reduce + 16K zfin + 1.5K tables

typedef __attribute__((ext_vector_type(8))) short short8;
typedef __attribute__((ext_vector_type(4))) float float4v;

__device__ __forceinline__ float sigf(float v) { return 1.0f / (1.0f + expf(-v)); }

__device__ __forceinline__ unsigned short bf_hi(float v, float* back) {
    __hip_bfloat16 b = __float2bfloat16(v);
    *back = __bfloat162float(b);
    union { __hip_bfloat16 b; unsigned short u; } cv; cv.b = b;
    return cv.u;
}

__global__ void zero_kernel(float* __restrict__ p, int n) {
    int i = blockIdx.x * 256 + threadIdx.x;
    if (i < n) p[i] = 0.0f;
}

// W (= [Wx;Wh], 1280 x 4096) -> B-frag order [nb(256)][ku(40)][lane(64)][j(8)], hi/lo
__global__ void packW_kernel(const float* __restrict__ Wx, const float* __restrict__ Wh,
                             unsigned short* __restrict__ W0f, unsigned short* __restrict__ W1f) {
    int e = blockIdx.x * 256 + threadIdx.x;
    if (e >= 1280 * 4096) return;
    int k = e >> 12, n = e & 4095;
    float w = (k < NDIN) ? Wx[(size_t)k * NG + n] : Wh[(size_t)(k - NDIN) * NG + n];
    float back;
    unsigned short w0 = bf_hi(w, &back);
    unsigned short w1 = bf_hi(w - back, &back);
    int nb = n >> 4, nl = n & 15, ku = k >> 5, kr = k & 31;
    int lane = (kr >> 3) * 16 + nl, j = kr & 7;
    size_t off = (((size_t)nb * 40 + ku) * 64 + lane) * 8 + j;
    W0f[off] = w0; W1f[off] = w1;
}

// x ([64][512][256]) -> A-frag order [t][ku(8)][mb(4)][lane(64)][j(8)], hi/lo
__global__ void packX_kernel(const float* __restrict__ x,
                             unsigned short* __restrict__ xf0, unsigned short* __restrict__ xf1) {
    int e = blockIdx.x * 256 + threadIdx.x;
    if (e >= NB * NT * NDIN) return;
    int k = e & 255, t = (e >> 8) & 511, m = e >> 17;
    float v = x[e];
    float back;
    unsigned short a0 = bf_hi(v, &back);
    unsigned short a1 = bf_hi(v - back, &back);
    int ku = k >> 5, kr = k & 31, mb = m >> 4;
    int lane = (kr >> 3) * 16 + (m & 15), j = kr & 7;
    size_t off = ((((size_t)t * 8 + ku) * 4 + mb) * 64 + lane) * 8 + j;
    xf0[off] = a0; xf1[off] = a1;
}

// Wo (1024 x 256) -> B-frag order [nb(16)][ku(32)][lane(64)][j(8)], hi/lo
__global__ void packWo_kernel(const float* __restrict__ Wo,
                              unsigned short* __restrict__ Wo0f, unsigned short* __restrict__ Wo1f) {
    int e = blockIdx.x * 256 + threadIdx.x;
    if (e >= NH * NDOUT) return;
    int k = e >> 8, n = e & 255;
    float w = Wo[e];
    float back;
    unsigned short w0 = bf_hi(w, &back);
    unsigned short w1 = bf_hi(w - back, &back);
    int nb = n >> 4, nl = n & 15, ku = k >> 5, kr = k & 31;
    int lane = (kr >> 3) * 16 + nl, j = kr & 7;
    size_t off = (((size_t)nb * 32 + ku) * 64 + lane) * 8 + j;
    Wo0f[off] = w0; Wo1f[off] = w1;
}

__device__ __forceinline__ const unsigned short* abase(
    const unsigned short* xf0, const unsigned short* xf1,
    const unsigned short* hf, int t, int buf, int ku, int v) {
    if (ku < 8) return (v ? xf1 : xf0) + ((size_t)t * 8 + ku) * 2048;
    return hf + ((size_t)(v * 2 + buf) * 32 + (ku - 8)) * 2048;
}

// One dispatch per timestep. All cross-block dataflow crosses the dispatch
// boundary (HW-coherent); everything inside a block is LDS/syncthreads-local.
__global__ __launch_bounds__(512, 2) void step_kernel(
    const unsigned short* __restrict__ W0f, const unsigned short* __restrict__ W1f,
    const unsigned short* __restrict__ xf0, const unsigned short* __restrict__ xf1,
    const unsigned short* __restrict__ Wo0f, const unsigned short* __restrict__ Wo1f,
    unsigned short* __restrict__ hf, float* __restrict__ cst,
    float* __restrict__ opart, const float* __restrict__ bias,
    const float* __restrict__ bo, float* __restrict__ out, int t)
{
    extern __shared__ char dynlds[];
    float* red  = (float*)dynlds;                    // [8][4096]
    float* zfin = (float*)(dynlds + 131072);         // [4096]
    const unsigned short** tabA = (const unsigned short**)(dynlds + 147456); // [96]
    const unsigned short** tabW = tabA + 96;

    const int bid = blockIdx.x, tid = threadIdx.x;
    const int lane = tid & 63, w = tid >> 6;
    const int buf = t & 1, nbuf = (t + 1) & 1;

    if (bid < 64) {
        // ---- z + block-local combine: 16 h-cols (jt), all 4 gates, all rows ----
        if (t >= NT) return;
        const int jt = bid;
        float4v acc[4][4];                            // [mb][gate]
        #pragma unroll
        for (int mb = 0; mb < 4; ++mb)
            #pragma unroll
            for (int g = 0; g < 4; ++g)
                acc[mb][g] = (float4v){0.f, 0.f, 0.f, 0.f};

        const int ku0 = w * 5;                        // wave-private K slice
        #pragma unroll
        for (int i = 0; i < 5; ++i) {
            const int ku = ku0 + i;
            short8 A0[4], A1[4], Wh[4], Wl[4];
            #pragma unroll
            for (int mb = 0; mb < 4; ++mb) {
                A0[mb] = *(const short8*)(abase(xf0, xf1, hf, t, buf, ku, 0) + mb * 512 + lane * 8);
                A1[mb] = *(const short8*)(abase(xf0, xf1, hf, t, buf, ku, 1) + mb * 512 + lane * 8);
            }
            #pragma unroll
            for (int g = 0; g < 4; ++g) {
                size_t off = (((size_t)(g * 64 + jt) * 40 + ku) * 64 + lane) * 8;
                Wh[g] = *(const short8*)(W0f + off);
                Wl[g] = *(const short8*)(W1f + off);
            }
            #pragma unroll
            for (int mb = 0; mb < 4; ++mb)
                #pragma unroll
                for (int g = 0; g < 4; ++g) {
                    acc[mb][g] = __builtin_amdgcn_mfma_f32_16x16x32_bf16(A0[mb], Wh[g], acc[mb][g], 0, 0, 0);
                    acc[mb][g] = __builtin_amdgcn_mfma_f32_16x16x32_bf16(A0[mb], Wl[g], acc[mb][g], 0, 0, 0);
                    acc[mb][g] = __builtin_amdgcn_mfma_f32_16x16x32_bf16(A1[mb], Wh[g], acc[mb][g], 0, 0, 0);
                }
        }

        // cross-wave splitK reduce via LDS
        {
            float* slab = red + w * 4096;
            #pragma unroll
            for (int mb = 0; mb < 4; ++mb)
                #pragma unroll
                for (int g = 0; g < 4; ++g)
                    *(float4v*)&slab[((mb * 4 + g) * 64 + lane) * 4] = acc[mb][g];
        }
        __syncthreads();
        for (int s = tid; s < 1024; s += 512) {
            float4v sum = (float4v){0.f, 0.f, 0.f, 0.f};
            #pragma unroll
            for (int ww = 0; ww < 8; ++ww)
                sum = sum + *(const float4v*)&red[ww * 4096 + s * 4];
            *(float4v*)&zfin[s * 4] = sum;
        }
        __syncthreads();

        // block-local gate math + cell update + h-frag write
        for (int e = tid; e < 1024; e += 512) {
            const int row = e >> 4, col = e & 15;
            const int j = jt * 16 + col;
            const int mb = row >> 4, q4 = (row >> 2) & 3, r = row & 3;
            const int ln = q4 * 16 + col;
            float zi = zfin[((mb * 4 + 0) * 64 + ln) * 4 + r] + bias[j];
            float zf = zfin[((mb * 4 + 1) * 64 + ln) * 4 + r] + bias[NH + j];
            float zg = zfin[((mb * 4 + 2) * 64 + ln) * 4 + r] + bias[2 * NH + j];
            float zo = zfin[((mb * 4 + 3) * 64 + ln) * 4 + r] + bias[3 * NH + j];
            float iv = sigf(zi), fv = sigf(zf), gv = tanhf(zg), ov = sigf(zo);
            const size_t ci = (size_t)row * NH + j;   // block-exclusive columns
            float cv = fv * cst[ci] + iv * gv;
            cst[ci] = cv;
            float hv = ov * tanhf(cv);
            float back;
            unsigned short h0 = bf_hi(hv, &back);
            unsigned short h1 = bf_hi(hv - back, &back);
            const int ku = j >> 5, kr = j & 31;
            const int lane2 = (kr >> 3) * 16 + (row & 15), jj = kr & 7;
            size_t base = (((size_t)nbuf * 32 + ku) * 4 + mb) * 512 + lane2 * 8 + jj;
            hf[base] = h0;
            hf[base + 131072] = h1;                   // v=1 stride
        }
    } else if (bid < 80) {
        // ---- projection of hf[buf] (= h of step t-1) -> opart[t&1] ----
        if (t < 1 || t > NT) return;
        const int pnb = bid - 64;
        for (int i = tid; i < 96; i += 512) {
            int q = i / 32, ku = i % 32, v = (q == 2);
            tabA[i] = hf + (((size_t)(v * 2 + buf) * 32 + ku) * 4) * 512;
            tabW[i] = ((q == 1) ? Wo1f : Wo0f) + (size_t)pnb * 32 * 512 + (size_t)ku * 512;
        }
        __syncthreads();
        const int pksl = w >> 2, mbw = w & 3;
        float4v pacc = (float4v){0.f, 0.f, 0.f, 0.f};
        #pragma unroll 6
        for (int i = pksl * 48; i < pksl * 48 + 48; ++i) {
            short8 A = *(const short8*)(tabA[i] + mbw * 512 + lane * 8);
            short8 B = *(const short8*)(tabW[i] + lane * 8);
            pacc = __builtin_amdgcn_mfma_f32_16x16x32_bf16(A, B, pacc, 0, 0, 0);
        }
        const int q4 = lane >> 4, nl16 = lane & 15;
        float* op = opart + (size_t)(t & 1) * 32768;
        #pragma unroll
        for (int r = 0; r < 4; ++r)
            op[((size_t)(pksl * 64 + mbw * 16 + q4 * 4 + r)) * NDOUT + pnb * 16 + nl16] = pacc[r];
    } else {
        // ---- out-reduce of opart[(t-1)&1] (= proj of h step t-2) -> row t-2 ----
        if (t < 2) return;
        const int ob = bid - 80;
        const float* op = opart + (size_t)((t - 1) & 1) * 32768;
        int idx = ob * 512 + tid;                     // [0,4096)
        int m = idx >> 6, oc4 = (idx & 63) * 4;
        float4v s0 = *(const float4v*)&op[(size_t)m * NDOUT + oc4];
        float4v s1 = *(const float4v*)&op[(size_t)(64 + m) * NDOUT + oc4];
        float4v bv = *(const float4v*)&bo[oc4];
        float4v v = s0 + s1 + bv;
        float4v rr;
        rr[0] = fmaxf(v[0], 0.f); rr[1] = fmaxf(v[1], 0.f);
        rr[2] = fmaxf(v[2], 0.f); rr[3] = fmaxf(v[3], 0.f);
        *(float4v*)&out[((size_t)m * NT + (t - 2)) * NDOUT + oc4] = rr;
    }
}

extern "C" void kernel_launch(void* const* d_in, const int* in_sizes, int n_in,
                              void* d_out, int out_size, void* d_ws, size_t ws_size,
                              hipStream_t stream) {
    const float* x  = (const float*)d_in[0];
    const float* Wx = (const float*)d_in[1];
    const float* Wh = (const float*)d_in[2];
    const float* b  = (const float*)d_in[3];
    const float* Wo = (const float*)d_in[4];
    const float* bo = (const float*)d_in[5];
    float* out = (float*)d_out;
    char* ws = (char*)d_ws;

    size_t off = 0;
    float* cst    = (float*)(ws + off);               off += (size_t)NB * NH * 4;               // 256 KB
    unsigned short* hf = (unsigned short*)(ws + off); off += (size_t)2 * 2 * 32 * 4 * 512 * 2;  // 512 KB
    size_t zero_floats = off / 4;                     // cst + hf zeroed
    float* opart = (float*)(ws + off);                off += (size_t)2 * 2 * NB * NDOUT * 4;    // 256 KB
    unsigned short* W0f = (unsigned short*)(ws + off); off += (size_t)1280 * 4096 * 2;
    unsigned short* W1f = (unsigned short*)(ws + off); off += (size_t)1280 * 4096 * 2;
    unsigned short* Wo0f = (unsigned short*)(ws + off); off += (size_t)NH * NDOUT * 2;
    unsigned short* Wo1f = (unsigned short*)(ws + off); off += (size_t)NH * NDOUT * 2;
    unsigned short* xf0 = (unsigned short*)(ws + off); off += (size_t)NB * NT * NDIN * 2;
    unsigned short* xf1 = (unsigned short*)(ws + off); off += (size_t)NB * NT * NDIN * 2;

    zero_kernel<<<(int)((zero_floats + 255) / 256), 256, 0, stream>>>((float*)ws, (int)zero_floats);
    packW_kernel<<<(1280 * 4096 + 255) / 256, 256, 0, stream>>>(Wx, Wh, W0f, W1f);
    packX_kernel<<<(NB * NT * NDIN + 255) / 256, 256, 0, stream>>>(x, xf0, xf1);
    packWo_kernel<<<(NH * NDOUT + 255) / 256, 256, 0, stream>>>(Wo, Wo0f, Wo1f);

    for (int t = 0; t <= NT + 1; ++t) {
        step_kernel<<<GRIDN, 512, LDSB, stream>>>(W0f, W1f, xf0, xf1, Wo0f, Wo1f,
                                                  hf, cst, opart, b, bo, out, t);
    }
}